// Round 2
// baseline (177.919 us; speedup 1.0000x reference)
//
#include <hip/hip_runtime.h>
#include <hip/hip_bf16.h>

typedef __hip_bfloat16 bf16;
// Device tensors are fp32 (reference dtypes); NaN in R1 proved inputs are not bf16.
typedef float in_t;
typedef float out_t;

#define CH    64
#define CIN1  32
#define CIN2  64
#define S1    186624   // 36*72*72
#define W1    5184     // 72*72
#define S2    23328    // 18*36*36
#define W2    1296     // 36*36
#define LDSTR 1297     // LDS row stride (1297%32=17, coprime -> conflict-free)
#define INV_NZ (1.0f/(288.0f + 1e-5f))

static __device__ __forceinline__ float ld(const float* p){ return *p; }
static __device__ __forceinline__ float b2f(bf16 v){ return __bfloat162float(v); }

// ---- weights: transpose so proj kernels read thread-uniform fp32 (scalarizable)
__global__ __launch_bounds__(256) void k_setup_w(
    const in_t* __restrict__ w_img, const in_t* __restrict__ b_img,
    const in_t* __restrict__ w_fea, const in_t* __restrict__ b_fea,
    float* __restrict__ wTi, float* __restrict__ bi,
    float* __restrict__ wTf, float* __restrict__ bff)
{
    int t = threadIdx.x;
    for (int idx = t; idx < CIN1*CH; idx += 256) {
        int c = idx >> 6, o = idx & 63;
        wTi[idx] = w_img[o*CIN1 + c];
    }
    for (int idx = t; idx < CIN2*CH; idx += 256) {
        int c = idx >> 6, o = idx & 63;
        wTf[idx] = w_fea[o*CIN2 + c];
    }
    if (t < CH) { bi[t] = b_img[t]; bff[t] = b_fea[t]; }
}

// ---- xq[o,s] = b[o] + sum_c w[o,c]*x[c,s]   (store bf16 to halve traffic)
__global__ __launch_bounds__(256) void k_proj_x(
    const in_t* __restrict__ x, const float* __restrict__ wT,
    const float* __restrict__ bias, bf16* __restrict__ xq)
{
    int s = blockIdx.x*256 + threadIdx.x;
    float acc[CH];
    #pragma unroll
    for (int o = 0; o < CH; ++o) acc[o] = 0.f;
    for (int c = 0; c < CIN1; ++c) {
        float xv = x[c*S1 + s];
        #pragma unroll
        for (int o = 0; o < CH; ++o) acc[o] += wT[c*CH + o] * xv;
    }
    #pragma unroll
    for (int o = 0; o < CH; ++o)
        xq[o*S1 + s] = __float2bfloat16(acc[o] + bias[o]);
}

// ---- yk[o,s] = b[o] + sum_c w[o,c]*y[c,s]   (store fp32, small)
__global__ __launch_bounds__(256) void k_proj_y(
    const in_t* __restrict__ y, const float* __restrict__ wT,
    const float* __restrict__ bias, float* __restrict__ yk)
{
    int s = blockIdx.x*256 + threadIdx.x;
    if (s >= S2) return;
    float acc[CH];
    #pragma unroll
    for (int o = 0; o < CH; ++o) acc[o] = 0.f;
    for (int c = 0; c < CIN2; ++c) {
        float yv = y[c*S2 + s];
        #pragma unroll
        for (int o = 0; o < CH; ++o) acc[o] += wT[c*CH + o] * yv;
    }
    #pragma unroll
    for (int o = 0; o < CH; ++o)
        yk[o*S2 + s] = acc[o] + bias[o];
}

// ---- AvgPool3d k3 s2 p1 count_include_pad=False: z(64,36,72,72) -> xd(64,18,36,36)
__global__ __launch_bounds__(256) void k_pool(const in_t* __restrict__ z, float* __restrict__ xd)
{
    int idx = blockIdx.x*256 + threadIdx.x;   // 64*23328 total, exact grid
    int c  = idx / S2;
    int r  = idx - c*S2;
    int od = r / W2;
    int r2 = r - od*W2;
    int oh = r2 / 36;
    int ow = r2 - oh*36;
    int dlo = max(2*od-1, 0), dhi = min(2*od+1, 35);
    int hlo = max(2*oh-1, 0), hhi = min(2*oh+1, 71);
    int wlo = max(2*ow-1, 0), whi = min(2*ow+1, 71);
    int cnt = (dhi-dlo+1)*(hhi-hlo+1)*(whi-wlo+1);
    const in_t* zc = z + c*S1;
    float s = 0.f;
    for (int d = dlo; d <= dhi; ++d)
        for (int h = hlo; h <= hhi; ++h)
            for (int w = wlo; w <= whi; ++w)
                s += zc[d*W1 + h*72 + w];
    xd[idx] = s / (float)cnt;
}

// ---- M[c,k1,k2] = sum_m Uxd[c,k1,m]*Uy[c,k2,m]  (m over 288 pooled patches)
// grid = 64 channels * 3 k1-groups of 27; block 256 (243 active), 3x3 register tiles
__global__ __launch_bounds__(256) void k_M(
    const float* __restrict__ xd, const float* __restrict__ yk, float* __restrict__ Mout)
{
    __shared__ float ylds[9*LDSTR];
    __shared__ float xlds[3*LDSTR];
    int c = blockIdx.x / 3, g = blockIdx.x - (blockIdx.x/3)*3;
    int t = threadIdx.x;
    int t1 = t / 27, t2 = t - (t/27)*27;
    int offx[3], offy[3];
    #pragma unroll
    for (int a = 0; a < 3; ++a) {
        int l1 = t1*3 + a;                       // local k1 (0..26)
        offx[a] = (l1/9)*LDSTR + (l1 - (l1/9)*9);
    }
    #pragma unroll
    for (int b = 0; b < 3; ++b) {
        int k2 = t2*3 + b;                       // 0..80
        offy[b] = (k2/9)*LDSTR + (k2 - (k2/9)*9);
    }
    float acc[3][3] = {};
    for (int ph2 = 0; ph2 < 2; ++ph2) {
        __syncthreads();
        for (int idx = t; idx < 9*W2; idx += 256) {
            int rr = idx / W2, col = idx - rr*W2;
            ylds[rr*LDSTR + col] = yk[c*S2 + (ph2*9 + rr)*W2 + col];
        }
        for (int idx = t; idx < 3*W2; idx += 256) {
            int rr = idx / W2, col = idx - rr*W2;
            xlds[rr*LDSTR + col] = xd[c*S2 + (ph2*9 + g*3 + rr)*W2 + col];
        }
        __syncthreads();
        if (t < 243) {
            for (int pw2 = 0; pw2 < 144; ++pw2) {
                int cb = pw2*9;
                float xv[3], yv[3];
                #pragma unroll
                for (int a = 0; a < 3; ++a) xv[a] = xlds[cb + offx[a]];
                #pragma unroll
                for (int b = 0; b < 3; ++b) yv[b] = ylds[cb + offy[b]];
                #pragma unroll
                for (int a = 0; a < 3; ++a)
                    #pragma unroll
                    for (int b = 0; b < 3; ++b) acc[a][b] += xv[a]*yv[b];
            }
        }
    }
    if (t < 243) {
        #pragma unroll
        for (int a = 0; a < 3; ++a) {
            int k1 = g*27 + t1*3 + a;
            #pragma unroll
            for (int b = 0; b < 3; ++b)
                Mout[c*6561 + k1*81 + (t2*3 + b)] = acc[a][b];
        }
    }
}

// ---- corr_blocks = M @ Ux / nz, fold9, LeakyReLU(0.2), out = dec*(1+act)
// grid = 64 ch * 4 ph * 16 groups of 36 patches; block 256 (243 active), 3x4 tiles
__global__ __launch_bounds__(256) void k_corr(
    const float* __restrict__ M, const bf16* __restrict__ xq,
    const in_t* __restrict__ z, out_t* __restrict__ out)
{
    __shared__ float Mlds[6561];
    __shared__ float plds[36*81];   // patch staging, reused for output staging
    int bid = blockIdx.x;
    int c   = bid >> 6;
    int rem = bid & 63;
    int ph  = rem >> 4;
    int grp = rem & 15;
    int colbase = grp*324;          // 36 patches * 9 cols
    int t = threadIdx.x;
    for (int idx = t; idx < 6561; idx += 256)
        Mlds[idx] = M[c*6561 + idx];
    for (int idx = t; idx < 2916; idx += 256) {
        int p = idx / 81, kk = idx - p*81;
        int i2 = kk / 9, j2 = kk - i2*9;
        plds[idx] = b2f(xq[c*S1 + (ph*9 + i2)*W1 + colbase + p*9 + j2]);
    }
    __syncthreads();
    float acc[3][4] = {};
    int kt = t % 27, pt = t / 27;
    if (t < 243) {
        const float* Mr0 = &Mlds[kt*3*81];
        const float* pr0 = &plds[pt*4*81];
        for (int k2 = 0; k2 < 81; ++k2) {
            float mv[3], xv[4];
            #pragma unroll
            for (int a = 0; a < 3; ++a) mv[a] = Mr0[a*81 + k2];
            #pragma unroll
            for (int b = 0; b < 4; ++b) xv[b] = pr0[b*81 + k2];
            #pragma unroll
            for (int a = 0; a < 3; ++a)
                #pragma unroll
                for (int b = 0; b < 4; ++b) acc[a][b] += mv[a]*xv[b];
        }
    }
    __syncthreads();
    if (t < 243) {
        #pragma unroll
        for (int b = 0; b < 4; ++b)
            #pragma unroll
            for (int a = 0; a < 3; ++a)
                plds[(pt*4 + b)*81 + kt*3 + a] = acc[a][b];
    }
    __syncthreads();
    for (int idx = t; idx < 2916; idx += 256) {
        int i = idx / 324, cc = idx - i*324;
        int p = cc / 9,   j  = cc - p*9;
        float corr = plds[p*81 + i*9 + j] * INV_NZ;
        float act  = corr > 0.f ? corr : 0.2f*corr;
        int ga = c*S1 + (ph*9 + i)*W1 + colbase + cc;
        float dec = z[ga];
        out[ga] = dec + act*dec;
    }
}

extern "C" void kernel_launch(void* const* d_in, const int* in_sizes, int n_in,
                              void* d_out, int out_size, void* d_ws, size_t ws_size,
                              hipStream_t stream)
{
    (void)in_sizes; (void)n_in; (void)out_size; (void)ws_size;
    const in_t* x     = (const in_t*)d_in[0];
    const in_t* y     = (const in_t*)d_in[1];
    const in_t* z     = (const in_t*)d_in[2];
    const in_t* w_img = (const in_t*)d_in[3];
    const in_t* b_img = (const in_t*)d_in[4];
    const in_t* w_fea = (const in_t*)d_in[5];
    const in_t* b_fea = (const in_t*)d_in[6];
    out_t* out = (out_t*)d_out;

    char* ws = (char*)d_ws;
    bf16*  xq  = (bf16*) (ws + 0);          // 64*186624*2 = 23,887,872
    float* yk  = (float*)(ws + 23887872);   // 64*23328*4  =  5,971,968
    float* xd  = (float*)(ws + 29859840);   // 64*23328*4  =  5,971,968
    float* Mb  = (float*)(ws + 35831808);   // 64*6561*4   =  1,679,616
    float* wTi = (float*)(ws + 37511424);   // 2048*4
    float* bi  = (float*)(ws + 37519616);   // 64*4
    float* wTf = (float*)(ws + 37519872);   // 4096*4
    float* bff = (float*)(ws + 37536256);   // 64*4

    hipLaunchKernelGGL(k_setup_w, dim3(1),            dim3(256), 0, stream,
                       w_img, b_img, w_fea, b_fea, wTi, bi, wTf, bff);
    hipLaunchKernelGGL(k_proj_x,  dim3(S1/256),       dim3(256), 0, stream, x, wTi, bi, xq);
    hipLaunchKernelGGL(k_proj_y,  dim3((S2+255)/256), dim3(256), 0, stream, y, wTf, bff, yk);
    hipLaunchKernelGGL(k_pool,    dim3((CH*S2)/256),  dim3(256), 0, stream, z, xd);
    hipLaunchKernelGGL(k_M,       dim3(192),          dim3(256), 0, stream, xd, yk, Mb);
    hipLaunchKernelGGL(k_corr,    dim3(4096),         dim3(256), 0, stream, Mb, xq, z, out);
}